// Round 1
// baseline (427.692 us; speedup 1.0000x reference)
//
#include <hip/hip_runtime.h>
#include <hip/hip_bf16.h>

// Problem constants (fixed by setup_inputs)
#define T_SZ 32
#define B_SZ 512
#define F_SZ 2048
#define H_SZ 2048
#define M_SZ (T_SZ * B_SZ)   // 16384 GEMM rows

typedef short bf16x8 __attribute__((ext_vector_type(8)));   // 8 bf16 = 4 VGPRs (MFMA A/B frag)
typedef float f32x4  __attribute__((ext_vector_type(4)));   // MFMA C/D frag
typedef unsigned short u16x8 __attribute__((ext_vector_type(8)));

__device__ __forceinline__ void gload_lds16(const void* g, void* l) {
    // async global->LDS, 16 B/lane (global_load_lds_dwordx4).
    // LDS dest semantics: wave-uniform base + lane*16 — layout below honors this.
    __builtin_amdgcn_global_load_lds(
        (const __attribute__((address_space(1))) unsigned int*)g,
        (__attribute__((address_space(3))) unsigned int*)l,
        16, 0, 0);
}

// ---------------- fp32 -> bf16 cast, 4 elems/thread ----------------
__global__ __launch_bounds__(256) void cvt_bf16_kernel(const float* __restrict__ in,
                                                       unsigned short* __restrict__ out,
                                                       int n4) {
    int i = blockIdx.x * 256 + threadIdx.x;
    if (i >= n4) return;
    float4 v = ((const float4*)in)[i];
    ushort4 o;
    o.x = __builtin_bit_cast(unsigned short, __float2bfloat16(v.x));
    o.y = __builtin_bit_cast(unsigned short, __float2bfloat16(v.y));
    o.z = __builtin_bit_cast(unsigned short, __float2bfloat16(v.z));
    o.w = __builtin_bit_cast(unsigned short, __float2bfloat16(v.w));
    ((ushort4*)out)[i] = o;
}

// ---------------- GEMM: C[m,n] = sum_k A[m,k] * Bt[n,k] + bias[n] ----------------
// m97 structure: 128x128 tile, BK=32, 4 waves (2x2), 4x4 16x16x32 MFMA per wave.
__global__ __launch_bounds__(256) void gemm_bt_kernel(const __hip_bfloat16* __restrict__ A,   // [M_SZ, F_SZ]
                                                      const __hip_bfloat16* __restrict__ Bt,  // [H_SZ, F_SZ]
                                                      const float* __restrict__ bias,         // [H_SZ]
                                                      __hip_bfloat16* __restrict__ C)         // [M_SZ, H_SZ] bf16
{
    __shared__ __align__(16) __hip_bfloat16 As[128 * 32];  // 8 KB, row-major [128][32]
    __shared__ __align__(16) __hip_bfloat16 Bs[128 * 32];  // 8 KB

    const int tid  = threadIdx.x;
    const int lane = tid & 63;
    const int wave = tid >> 6;
    const int wm   = wave >> 1;          // 0..1 wave row
    const int wn   = wave & 1;           // 0..1 wave col
    const int m0   = blockIdx.y * 128;
    const int n0   = blockIdx.x * 128;
    const int quad = lane >> 4;          // 0..3
    const int r16  = lane & 15;          // 0..15

    f32x4 acc[4][4] = {};

    for (int k0 = 0; k0 < F_SZ; k0 += 32) {
        __syncthreads();   // previous tile fully consumed before overwrite
        #pragma unroll
        for (int j = 0; j < 2; ++j) {
            int chunk = j * 256 + tid;          // 512 x 16B chunks per 8KB tile
            int row   = chunk >> 2;             // 0..127
            int kp    = (chunk & 3) << 3;       // 0,8,16,24
            gload_lds16(A  + (size_t)(m0 + row) * F_SZ + k0 + kp, (void*)(As + chunk * 8));
            gload_lds16(Bt + (size_t)(n0 + row) * F_SZ + k0 + kp, (void*)(Bs + chunk * 8));
        }
        __syncthreads();   // compiler inserts s_waitcnt vmcnt(0) before barrier

        bf16x8 af[4], bq[4];
        #pragma unroll
        for (int i = 0; i < 4; ++i) {
            af[i] = *(const bf16x8*)(As + (wm * 64 + i * 16 + r16) * 32 + quad * 8);
            bq[i] = *(const bf16x8*)(Bs + (wn * 64 + i * 16 + r16) * 32 + quad * 8);
        }
        #pragma unroll
        for (int mi = 0; mi < 4; ++mi)
            #pragma unroll
            for (int ni = 0; ni < 4; ++ni)
                acc[mi][ni] = __builtin_amdgcn_mfma_f32_16x16x32_bf16(af[mi], bq[ni], acc[mi][ni], 0, 0, 0);
    }

    // epilogue: C/D layout col = lane&15, row = quad*4 + reg (m89-verified)
    #pragma unroll
    for (int ni = 0; ni < 4; ++ni) {
        const int gn = n0 + wn * 64 + ni * 16 + r16;
        const float bv = bias[gn];
        #pragma unroll
        for (int mi = 0; mi < 4; ++mi) {
            const int gm = m0 + wm * 64 + mi * 16 + quad * 4;
            #pragma unroll
            for (int r = 0; r < 4; ++r)
                C[(size_t)(gm + r) * H_SZ + gn] = __float2bfloat16(acc[mi][ni][r] + bv);
        }
    }
}

// ---------------- fused L2-normalize (dim=-1) + LIF scan + spike/count ----------------
// One block per batch element b. 256 threads, 8 columns each.
__global__ __launch_bounds__(256) void norm_lif_kernel(const __hip_bfloat16* __restrict__ cur, // [M_SZ, H_SZ]
                                                       float* __restrict__ spk,                // [T,B,H]
                                                       float* __restrict__ cnt)                // [B,H]
{
    const int b    = blockIdx.x;
    const int tid  = threadIdx.x;
    const int lane = tid & 63;
    const int wv   = tid >> 6;

    __shared__ float wred[T_SZ][4];
    __shared__ float ninv[T_SZ];

    // ---- phase 1: sum of squares over H for each t (loads batched for MLP) ----
    float ss[T_SZ];
    #pragma unroll
    for (int t = 0; t < T_SZ; ++t) {
        const u16x8 pk = *(const u16x8*)(cur + (size_t)(t * B_SZ + b) * H_SZ + tid * 8);
        float s = 0.f;
        #pragma unroll
        for (int j = 0; j < 8; ++j) {
            float f = __uint_as_float(((unsigned)pk[j]) << 16);
            s += f * f;
        }
        ss[t] = s;
    }
    #pragma unroll
    for (int t = 0; t < T_SZ; ++t) {
        float s = ss[t];
        #pragma unroll
        for (int off = 32; off >= 1; off >>= 1) s += __shfl_down(s, off, 64);
        if (lane == 0) wred[t][wv] = s;
    }
    __syncthreads();
    if (tid < T_SZ) {
        float s = wred[tid][0] + wred[tid][1] + wred[tid][2] + wred[tid][3];
        ninv[tid] = 1.0f / fmaxf(sqrtf(s), 1e-12f);
    }
    __syncthreads();

    // ---- phase 2: LIF scan over T, 8 columns per thread ----
    float v[8]   = {0, 0, 0, 0, 0, 0, 0, 0};
    float cn8[8] = {0, 0, 0, 0, 0, 0, 0, 0};
    #pragma unroll
    for (int t = 0; t < T_SZ; ++t) {
        const size_t off = (size_t)(t * B_SZ + b) * H_SZ + tid * 8;
        const u16x8 pk = *(const u16x8*)(cur + off);
        const float inv = ninv[t];
        float so[8];
        #pragma unroll
        for (int j = 0; j < 8; ++j) {
            float c = __uint_as_float(((unsigned)pk[j]) << 16) * inv;
            v[j] += (c - v[j]) * 0.5f;                  // LIF charge, tau=2
            float s = (v[j] >= 1.0f) ? 1.0f : 0.0f;     // Heaviside(v - v_th)
            so[j] = s;
            cn8[j] += s;
            v[j] = (s != 0.f) ? 0.f : v[j];             // hard reset to 0
        }
        *(float4*)(spk + off)     = make_float4(so[0], so[1], so[2], so[3]);
        *(float4*)(spk + off + 4) = make_float4(so[4], so[5], so[6], so[7]);
    }
    const size_t coff = (size_t)b * H_SZ + tid * 8;
    *(float4*)(cnt + coff)     = make_float4(cn8[0], cn8[1], cn8[2], cn8[3]);
    *(float4*)(cnt + coff + 4) = make_float4(cn8[4], cn8[5], cn8[6], cn8[7]);
}

extern "C" void kernel_launch(void* const* d_in, const int* in_sizes, int n_in,
                              void* d_out, int out_size, void* d_ws, size_t ws_size,
                              hipStream_t stream) {
    const float* x    = (const float*)d_in[0];   // [T,B,F] fp32
    const float* W    = (const float*)d_in[1];   // [H,F]  fp32
    const float* bias = (const float*)d_in[2];   // [H]    fp32

    float* spk = (float*)d_out;                          // [T,B,H]
    float* cnt = spk + (size_t)T_SZ * B_SZ * H_SZ;       // [B,H]

    char* ws = (char*)d_ws;
    __hip_bfloat16* xb   = (__hip_bfloat16*)ws;                                            // 67.1 MB
    __hip_bfloat16* Wb   = (__hip_bfloat16*)(ws + (size_t)M_SZ * F_SZ * 2);                // 8.4 MB
    __hip_bfloat16* curb = (__hip_bfloat16*)(ws + (size_t)M_SZ * F_SZ * 2
                                                + (size_t)H_SZ * F_SZ * 2);                // 67.1 MB

    cvt_bf16_kernel<<<(M_SZ * F_SZ) / 1024, 256, 0, stream>>>(x, (unsigned short*)xb, (M_SZ * F_SZ) / 4);
    cvt_bf16_kernel<<<(H_SZ * F_SZ) / 1024, 256, 0, stream>>>(W, (unsigned short*)Wb, (H_SZ * F_SZ) / 4);
    gemm_bt_kernel<<<dim3(H_SZ / 128, M_SZ / 128), 256, 0, stream>>>(xb, Wb, bias, curb);
    norm_lif_kernel<<<B_SZ, 256, 0, stream>>>(curb, spk, cnt);
}